// Round 17
// baseline (167.593 us; speedup 1.0000x reference)
//
#include <hip/hip_runtime.h>
#include <math.h>

#define DCOLS 128
#define ROUTIT 6
#define EPS_N 1e-12f
#define EPP 4       // edges per wave pass (16 lanes per edge)
#define NCACHE 5    // passes with z cached in LDS (20 edges; P(deg>20)~1.5%)
#define CE (EPP * NCACHE)
#define CAP 48      // per-node slot capacity (P(deg>48) ~ 1e-15 per node)
#define LOG2E 1.44269504f

typedef _Float16 h2 __attribute__((ext_vector_type(2)));
typedef _Float16 h8 __attribute__((ext_vector_type(8)));

__device__ __forceinline__ float shflx(float v, int mask) {
    return __shfl_xor(v, mask, 64);
}

// Butterfly sums on the VALU pipe via DPP.
// 0xB1 = quad_perm(1,0,3,2) == xor1; 0x4E = quad_perm(2,3,0,1) == xor2.
// 0x128 = row_ror:8: within a 16-lane row, (i+8)%16 == i^8 exactly -> xor8.
// 0x124 = row_ror:4: (i+4)%16 == i^4 or i^4^8; equals xor4 PROVIDED the value
// is already xor8-invariant (so apply AFTER the xor8 step).
template <int CTRL>
__device__ __forceinline__ float dpp_sum(float x) {
    int yi = __builtin_amdgcn_mov_dpp(__builtin_bit_cast(int, x), CTRL, 0xF, 0xF, true);
    return x + __builtin_bit_cast(float, yi);
}

// xor16 / xor32 butterfly sums: PROVEN __shfl_xor path.
// NOTE (round 14/15 post-mortem): permlane16/32_swap with the same value for
// both operands aliases to an in-place row swap (r[0]==r[1]) -> 2*swapped(x).
// Do not reintroduce without distinct operands.
__device__ __forceinline__ float xor16_sum(float x) { return x + shflx(x, 16); }
__device__ __forceinline__ float xor32_sum(float x) { return x + shflx(x, 32); }

// async global->LDS, 16B per lane; LDS dest = wave-uniform base + lane*16.
__device__ __forceinline__ void gload_lds16(const void* g, void* l) {
    __builtin_amdgcn_global_load_lds(
        (const __attribute__((address_space(1))) void*)g,
        (__attribute__((address_space(3))) void*)l, 16, 0, 0);
}

// Fused prep: blocks [0, nb_norm) L2-normalize each 16-wide capsule of x and
// pack to f16 (wave per node, lane l owns cols 2l,2l+1). Blocks >= nb_norm
// fill the per-target slot table with one atomic pass. Block 0's first 64
// threads also zero the dummy row n (read by routing for empty slots).
__global__ void prep_kernel(const float* __restrict__ x, h2* __restrict__ xh,
                            const int* __restrict__ src, const int* __restrict__ trg,
                            int* __restrict__ cnt, int* __restrict__ slots,
                            int n, int m, int nb_norm) {
    if ((int)blockIdx.x < nb_norm) {
        if (blockIdx.x == 0 && threadIdx.x < 64) {
            h2 zz = {};
            xh[(size_t)n * 64 + threadIdx.x] = zz;   // dummy row
        }
        int node = (int)((blockIdx.x * blockDim.x + threadIdx.x) >> 6);
        int lane = threadIdx.x & 63;
        if (node >= n) return;
        float2 v = *reinterpret_cast<const float2*>(x + (size_t)node * DCOLS + 2 * lane);
        float sq = v.x * v.x + v.y * v.y;
        sq += shflx(sq, 1); sq += shflx(sq, 2); sq += shflx(sq, 4);  // capsule = 8 lanes
        float inv = 1.0f / fmaxf(sqrtf(sq), EPS_N);
        h2 o;
        o[0] = (_Float16)(v.x * inv);
        o[1] = (_Float16)(v.y * inv);
        xh[(size_t)node * 64 + lane] = o;
    } else {
        int e = (blockIdx.x - nb_norm) * blockDim.x + threadIdx.x;
        if (e < m) {
            int t = trg[e];
            int p = atomicAdd(&cnt[t], 1);
            if (p < CAP) slots[t * CAP + p] = src[e];
        }
    }
}

// One edge slot. z = lane's 8 flat cols (f16) of the normalized source row
// (all-zero for empty slots -> p=0, ex=1, zs=8: w*0 contribution, no NaN).
// Snh[t] = packed S (pre-scaled by log2e) for cols 2t,2t+1. p-reduce over the
// capsule's 2 lanes (xor1), softmax-sum over 8 capsules (xor2, xor8, xor4 —
// all DPP on the VALU pipe; ordering: xor4 after xor8, see dpp_sum note).
// No max-subtraction: unit capsules, |S[j]| <= 8 -> |p*log2e| <= 47, f32-safe.
__device__ __forceinline__ void process_edge(const h8 z, const h2 Snh[4], float acc[8]) {
    float part = 0.0f;
    part = __builtin_amdgcn_fdot2(__builtin_shufflevector(z, z, 0, 1), Snh[0], part, false);
    part = __builtin_amdgcn_fdot2(__builtin_shufflevector(z, z, 2, 3), Snh[1], part, false);
    part = __builtin_amdgcn_fdot2(__builtin_shufflevector(z, z, 4, 5), Snh[2], part, false);
    part = __builtin_amdgcn_fdot2(__builtin_shufflevector(z, z, 6, 7), Snh[3], part, false);
    float p = dpp_sum<0xB1>(part);             // xor1 (VALU)
    float ex = exp2f(p);                       // S pre-scaled by log2e
    float zs = dpp_sum<0x4E>(ex);              // xor2 (VALU)
    zs = dpp_sum<0x128>(zs);                   // xor8 (VALU, row_ror:8 exact)
    zs = dpp_sum<0x124>(zs);                   // xor4 (VALU, valid after xor8)
    float w = ex * __builtin_amdgcn_rcpf(zs);
#pragma unroll
    for (int q = 0; q < 8; ++q) acc[q] = fmaf(w, (float)z[q], acc[q]);  // v_fma_mix
}

// Wave per node (4 waves/block). lane = 16*slot + l16. Lane owns FLAT cols
// 8*l16..8*l16+7. S[l16] is lane-local; p-term for flat col f uses S[f & 15].
// z rows DMA'd to LDS (global_load_lds). Per-edge softmax entirely on VALU
// (DPP); DS pipe only carries S-broadcast, zcache reads, cross-slot reduce.
__global__ __launch_bounds__(256) void routing_kernel(
    const h2* __restrict__ xh, const int* __restrict__ cnt,
    const int* __restrict__ slots, float* __restrict__ out, int n)
{
    __shared__ h8 zcache[4][CE][16];
    int wave = threadIdx.x >> 6;
    int node = blockIdx.x * 4 + wave;
    int lane = threadIdx.x & 63;
    if (node >= n) return;
    int l16 = lane & 15;
    int slot = lane >> 4;

    const h8* xrows = reinterpret_cast<const h8*>(xh);  // 16 h8 per row

    h8 xvh = xrows[(size_t)node * 16 + l16];
    float cc[8];
#pragma unroll
    for (int q = 0; q < 8; ++q) cc[q] = (float)xvh[q];

    int deg = min(cnt[node], CAP);
    int base = node * CAP;
    int np = min((deg + EPP - 1) / EPP, NCACHE);   // active cached passes

    // One coalesced slot-index load (lane < CE), broadcast per pass via shfl.
    int idxl = n;
    if (lane < CE && lane < deg) idxl = slots[base + lane];

    // Issue all active passes' DMA back-to-back; lane L of pass pp fills
    // zcache[wave][pp*EPP + (L>>4)][L&15] = base + L*16 (lane-linear).
#pragma unroll 1
    for (int pp = 0; pp < np; ++pp) {
        int u = __shfl(idxl, pp * EPP + slot, 64);  // == n when eidx >= deg
        const char* gsrc = (const char*)xh + ((size_t)u * 256 + l16 * 16);
        gload_lds16(gsrc, &zcache[wave][pp * EPP][0]);
    }
    asm volatile("s_waitcnt vmcnt(0)" ::: "memory");

    int src_base = (lane & ~15) | (8 * (l16 & 1));

    for (int t = 0; t < ROUTIT; ++t) {
        // S[l16] lane-local (scaled by log2e); pair-pack (xor1 DPP + pkrtz),
        // then 4 bpermutes fetch the 8 S values this lane needs.
        float Sl = ((cc[0] + cc[1]) + (cc[2] + cc[3])) + ((cc[4] + cc[5]) + (cc[6] + cc[7]));
        Sl *= LOG2E;
        int Spi = __builtin_amdgcn_mov_dpp(__builtin_bit_cast(int, Sl), 0xB1, 0xF, 0xF, true);
        float Sp = __builtin_bit_cast(float, Spi);
        auto Wl = __builtin_amdgcn_cvt_pkrtz(Sl, Sp);  // even lanes: (S[e], S[e+1])
        int Wi = __builtin_bit_cast(int, Wl);
        h2 Snh[4];
#pragma unroll
        for (int tq = 0; tq < 4; ++tq)
            Snh[tq] = __builtin_bit_cast(h2, __shfl(Wi, src_base + 2 * tq, 64));

        float acc[8];
#pragma unroll
        for (int q = 0; q < 8; ++q) acc[q] = 0.0f;

        // unroll-1: exactly one z-row live at a time (VGPR control).
#pragma unroll 1
        for (int pp = 0; pp < np; ++pp) {
            h8 z = zcache[wave][pp * EPP + slot][l16];
            process_edge(z, Snh, acc);
        }
        // streaming tail (P(deg>20) ~ 1.5% of nodes)
#pragma unroll 1
        for (int eb = CE; eb < deg; eb += EPP) {
            int eidx = eb + slot;
            h8 z = {};
            if (eidx < deg) z = xrows[(size_t)slots[base + eidx] * 16 + l16];
            process_edge(z, Snh, acc);
        }

        // reduce across the 4 edge slots (proven shfl path)
#pragma unroll
        for (int q = 0; q < 8; ++q) {
            acc[q] = xor16_sum(acc[q]);
            acc[q] = xor32_sum(acc[q]);
        }
#pragma unroll
        for (int q = 0; q < 8; ++q) cc[q] = acc[q] + (float)xvh[q];

        if (t < ROUTIT - 1) {
            float sq = cc[0] * cc[0];
#pragma unroll
            for (int q = 1; q < 8; ++q) sq = fmaf(cc[q], cc[q], sq);
            sq = dpp_sum<0xB1>(sq);   // capsule = 2 adjacent lanes (xor1)
            float inv = 1.0f / fmaxf(sqrtf(sq), EPS_N);
#pragma unroll
            for (int q = 0; q < 8; ++q) cc[q] *= inv;
        }
    }

    if (slot == 0) {
        float4* orow = reinterpret_cast<float4*>(out + (size_t)node * DCOLS + 8 * l16);
        orow[0] = make_float4(cc[0], cc[1], cc[2], cc[3]);
        orow[1] = make_float4(cc[4], cc[5], cc[6], cc[7]);
    }
}

extern "C" void kernel_launch(void* const* d_in, const int* in_sizes, int n_in,
                              void* d_out, int out_size, void* d_ws, size_t ws_size,
                              hipStream_t stream) {
    const float* x = (const float*)d_in[0];
    const int* ei = (const int*)d_in[1];
    float* out = (float*)d_out;
    int n = in_sizes[0] / DCOLS;
    int m = in_sizes[1] / 2;
    const int* src = ei;
    const int* trg = ei + m;

    char* ws = (char*)d_ws;
    h2* xh = (h2*)ws;             ws += (size_t)(n + 1) * DCOLS * sizeof(_Float16);
    int* cnt = (int*)ws;          ws += (size_t)n * sizeof(int);
    int* slots = (int*)ws;        ws += (size_t)n * CAP * sizeof(int);

    (void)hipMemsetAsync(cnt, 0, (size_t)n * sizeof(int), stream);

    int nb_norm = (n + 3) / 4;
    int nb_fill = (m + 255) / 256;
    prep_kernel<<<nb_norm + nb_fill, 256, 0, stream>>>(x, xh, src, trg, cnt, slots,
                                                       n, m, nb_norm);
    routing_kernel<<<(n + 3) / 4, 256, 0, stream>>>(xh, cnt, slots, out, n);
}

// Round 18
// 165.953 us; speedup vs baseline: 1.0099x; 1.0099x over previous
//
#include <hip/hip_runtime.h>
#include <math.h>

#define DCOLS 128
#define ROUTIT 6
#define EPS_N 1e-12f
#define EPP 4       // edges per wave pass (16 lanes per edge)
#define NCACHE 5    // passes with z cached in LDS (20 edges; P(deg>20)~1.5%)
#define CE (EPP * NCACHE)
#define CAP 48      // per-node slot capacity (P(deg>48) ~ 1e-15 per node)
#define LOG2E 1.44269504f

typedef _Float16 h2 __attribute__((ext_vector_type(2)));
typedef _Float16 h8 __attribute__((ext_vector_type(8)));

__device__ __forceinline__ float shflx(float v, int mask) {
    return __shfl_xor(v, mask, 64);
}

// Butterfly sums on the VALU pipe via DPP.
// 0xB1 = quad_perm(1,0,3,2) == xor1; 0x4E = quad_perm(2,3,0,1) == xor2.
// 0x128 = row_ror:8: within a 16-lane row, (i+8)%16 == i^8 exactly -> xor8.
// 0x124 = row_ror:4: (i+4)%16 == i^4 or i^4^8; equals xor4 PROVIDED the value
// is already xor8-invariant (so apply AFTER the xor8 step).
template <int CTRL>
__device__ __forceinline__ float dpp_sum(float x) {
    int yi = __builtin_amdgcn_mov_dpp(__builtin_bit_cast(int, x), CTRL, 0xF, 0xF, true);
    return x + __builtin_bit_cast(float, yi);
}

// xor16 / xor32 butterfly sums: PROVEN __shfl_xor path.
// NOTE (round 14/15 post-mortem): permlane16/32_swap with the same value for
// both operands aliases to an in-place row swap (r[0]==r[1]) -> 2*swapped(x).
// Do not reintroduce without distinct operands.
__device__ __forceinline__ float xor16_sum(float x) { return x + shflx(x, 16); }
__device__ __forceinline__ float xor32_sum(float x) { return x + shflx(x, 32); }

// async global->LDS, 16B per lane; LDS dest = wave-uniform base + lane*16.
__device__ __forceinline__ void gload_lds16(const void* g, void* l) {
    __builtin_amdgcn_global_load_lds(
        (const __attribute__((address_space(1))) void*)g,
        (__attribute__((address_space(3))) void*)l, 16, 0, 0);
}

// Fused prep: blocks [0, nb_norm) L2-normalize each 16-wide capsule of x and
// pack to f16 (wave per node, lane l owns cols 2l,2l+1). Blocks >= nb_norm
// fill the per-target slot table with one atomic pass. Block 0's first 64
// threads also zero the dummy row n (read by routing for empty slots).
__global__ void prep_kernel(const float* __restrict__ x, h2* __restrict__ xh,
                            const int* __restrict__ src, const int* __restrict__ trg,
                            int* __restrict__ cnt, int* __restrict__ slots,
                            int n, int m, int nb_norm) {
    if ((int)blockIdx.x < nb_norm) {
        if (blockIdx.x == 0 && threadIdx.x < 64) {
            h2 zz = {};
            xh[(size_t)n * 64 + threadIdx.x] = zz;   // dummy row
        }
        int node = (int)((blockIdx.x * blockDim.x + threadIdx.x) >> 6);
        int lane = threadIdx.x & 63;
        if (node >= n) return;
        float2 v = *reinterpret_cast<const float2*>(x + (size_t)node * DCOLS + 2 * lane);
        float sq = v.x * v.x + v.y * v.y;
        sq += shflx(sq, 1); sq += shflx(sq, 2); sq += shflx(sq, 4);  // capsule = 8 lanes
        float inv = 1.0f / fmaxf(sqrtf(sq), EPS_N);
        h2 o;
        o[0] = (_Float16)(v.x * inv);
        o[1] = (_Float16)(v.y * inv);
        xh[(size_t)node * 64 + lane] = o;
    } else {
        int e = (blockIdx.x - nb_norm) * blockDim.x + threadIdx.x;
        if (e < m) {
            int t = trg[e];
            int p = atomicAdd(&cnt[t], 1);
            if (p < CAP) slots[t * CAP + p] = src[e];
        }
    }
}

// One edge slot. z = lane's 8 flat cols (f16) of the normalized source row
// (all-zero for empty slots -> p=0, ex=1, zs=8: w*0 contribution, no NaN).
// Snh[t] = packed S (pre-scaled by log2e) for cols 2t,2t+1. p-reduce over the
// capsule's 2 lanes (xor1), softmax-sum over 8 capsules (xor2, xor8, xor4 —
// all DPP on the VALU pipe; ordering: xor4 after xor8, see dpp_sum note).
// No max-subtraction: unit capsules, |S[j]| <= 8 -> |p*log2e| <= 47, f32-safe.
__device__ __forceinline__ void process_edge(const h8 z, const h2 Snh[4], float acc[8]) {
    float part = 0.0f;
    part = __builtin_amdgcn_fdot2(__builtin_shufflevector(z, z, 0, 1), Snh[0], part, false);
    part = __builtin_amdgcn_fdot2(__builtin_shufflevector(z, z, 2, 3), Snh[1], part, false);
    part = __builtin_amdgcn_fdot2(__builtin_shufflevector(z, z, 4, 5), Snh[2], part, false);
    part = __builtin_amdgcn_fdot2(__builtin_shufflevector(z, z, 6, 7), Snh[3], part, false);
    float p = dpp_sum<0xB1>(part);             // xor1 (VALU)
    float ex = exp2f(p);                       // S pre-scaled by log2e
    float zs = dpp_sum<0x4E>(ex);              // xor2 (VALU)
    zs = dpp_sum<0x128>(zs);                   // xor8 (VALU, row_ror:8 exact)
    zs = dpp_sum<0x124>(zs);                   // xor4 (VALU, valid after xor8)
    float w = ex * __builtin_amdgcn_rcpf(zs);
#pragma unroll
    for (int q = 0; q < 8; ++q) acc[q] = fmaf(w, (float)z[q], acc[q]);  // v_fma_mix
}

// Wave per node (4 waves/block). lane = 16*slot + l16. Lane owns FLAT cols
// 8*l16..8*l16+7. S[l16] is lane-local; p-term for flat col f uses S[f & 15].
// z rows DMA'd to LDS (global_load_lds). Per-edge softmax entirely on VALU
// (DPP); DS pipe only carries S-broadcast, zcache reads, cross-slot reduce.
__global__ __launch_bounds__(256) void routing_kernel(
    const h2* __restrict__ xh, const int* __restrict__ cnt,
    const int* __restrict__ slots, float* __restrict__ out, int n)
{
    __shared__ h8 zcache[4][CE][16];
    int wave = threadIdx.x >> 6;
    int node = blockIdx.x * 4 + wave;
    int lane = threadIdx.x & 63;
    if (node >= n) return;
    int l16 = lane & 15;
    int slot = lane >> 4;

    const h8* xrows = reinterpret_cast<const h8*>(xh);  // 16 h8 per row

    h8 xvh = xrows[(size_t)node * 16 + l16];
    float cc[8];
#pragma unroll
    for (int q = 0; q < 8; ++q) cc[q] = (float)xvh[q];

    int deg = min(cnt[node], CAP);
    int base = node * CAP;
    int np = min((deg + EPP - 1) / EPP, NCACHE);   // active cached passes

    // One coalesced slot-index load (lane < CE), broadcast per pass via shfl.
    int idxl = n;
    if (lane < CE && lane < deg) idxl = slots[base + lane];

    // Issue all active passes' DMA back-to-back; lane L of pass pp fills
    // zcache[wave][pp*EPP + (L>>4)][L&15] = base + L*16 (lane-linear).
#pragma unroll 1
    for (int pp = 0; pp < np; ++pp) {
        int u = __shfl(idxl, pp * EPP + slot, 64);  // == n when eidx >= deg
        const char* gsrc = (const char*)xh + ((size_t)u * 256 + l16 * 16);
        gload_lds16(gsrc, &zcache[wave][pp * EPP][0]);
    }
    asm volatile("s_waitcnt vmcnt(0)" ::: "memory");

    int src_base = (lane & ~15) | (8 * (l16 & 1));

    for (int t = 0; t < ROUTIT; ++t) {
        // S[l16] lane-local (scaled by log2e); pair-pack (xor1 DPP + pkrtz),
        // then 4 bpermutes fetch the 8 S values this lane needs.
        float Sl = ((cc[0] + cc[1]) + (cc[2] + cc[3])) + ((cc[4] + cc[5]) + (cc[6] + cc[7]));
        Sl *= LOG2E;
        int Spi = __builtin_amdgcn_mov_dpp(__builtin_bit_cast(int, Sl), 0xB1, 0xF, 0xF, true);
        float Sp = __builtin_bit_cast(float, Spi);
        auto Wl = __builtin_amdgcn_cvt_pkrtz(Sl, Sp);  // even lanes: (S[e], S[e+1])
        int Wi = __builtin_bit_cast(int, Wl);
        h2 Snh[4];
#pragma unroll
        for (int tq = 0; tq < 4; ++tq)
            Snh[tq] = __builtin_bit_cast(h2, __shfl(Wi, src_base + 2 * tq, 64));

        float acc[8];
#pragma unroll
        for (int q = 0; q < 8; ++q) acc[q] = 0.0f;

        // unroll-1: exactly one z-row live at a time (VGPR control).
#pragma unroll 1
        for (int pp = 0; pp < np; ++pp) {
            h8 z = zcache[wave][pp * EPP + slot][l16];
            process_edge(z, Snh, acc);
        }
        // streaming tail (P(deg>20) ~ 1.5% of nodes)
#pragma unroll 1
        for (int eb = CE; eb < deg; eb += EPP) {
            int eidx = eb + slot;
            h8 z = {};
            if (eidx < deg) z = xrows[(size_t)slots[base + eidx] * 16 + l16];
            process_edge(z, Snh, acc);
        }

        // reduce across the 4 edge slots (proven shfl path)
#pragma unroll
        for (int q = 0; q < 8; ++q) {
            acc[q] = xor16_sum(acc[q]);
            acc[q] = xor32_sum(acc[q]);
        }
#pragma unroll
        for (int q = 0; q < 8; ++q) cc[q] = acc[q] + (float)xvh[q];

        if (t < ROUTIT - 1) {
            float sq = cc[0] * cc[0];
#pragma unroll
            for (int q = 1; q < 8; ++q) sq = fmaf(cc[q], cc[q], sq);
            sq = dpp_sum<0xB1>(sq);   // capsule = 2 adjacent lanes (xor1)
            float inv = 1.0f / fmaxf(sqrtf(sq), EPS_N);
#pragma unroll
            for (int q = 0; q < 8; ++q) cc[q] *= inv;
        }
    }

    if (slot == 0) {
        float4* orow = reinterpret_cast<float4*>(out + (size_t)node * DCOLS + 8 * l16);
        orow[0] = make_float4(cc[0], cc[1], cc[2], cc[3]);
        orow[1] = make_float4(cc[4], cc[5], cc[6], cc[7]);
    }
}

extern "C" void kernel_launch(void* const* d_in, const int* in_sizes, int n_in,
                              void* d_out, int out_size, void* d_ws, size_t ws_size,
                              hipStream_t stream) {
    const float* x = (const float*)d_in[0];
    const int* ei = (const int*)d_in[1];
    float* out = (float*)d_out;
    int n = in_sizes[0] / DCOLS;
    int m = in_sizes[1] / 2;
    const int* src = ei;
    const int* trg = ei + m;

    char* ws = (char*)d_ws;
    h2* xh = (h2*)ws;             ws += (size_t)(n + 1) * DCOLS * sizeof(_Float16);
    int* cnt = (int*)ws;          ws += (size_t)n * sizeof(int);
    int* slots = (int*)ws;        ws += (size_t)n * CAP * sizeof(int);

    (void)hipMemsetAsync(cnt, 0, (size_t)n * sizeof(int), stream);

    int nb_norm = (n + 3) / 4;
    int nb_fill = (m + 255) / 256;
    prep_kernel<<<nb_norm + nb_fill, 256, 0, stream>>>(x, xh, src, trg, cnt, slots,
                                                       n, m, nb_norm);
    routing_kernel<<<(n + 3) / 4, 256, 0, stream>>>(xh, cnt, slots, out, n);
}

// Round 19
// 158.589 us; speedup vs baseline: 1.0568x; 1.0464x over previous
//
#include <hip/hip_runtime.h>
#include <math.h>

#define DCOLS 128
#define ROUTIT 6
#define EPS_N 1e-12f
#define EPP 4       // edges per wave pass (16 lanes per edge)
#define NCACHE 5    // passes with z cached in LDS (20 edges; P(deg>20)~1.5%)
#define CE (EPP * NCACHE)
#define CAP 48      // per-node slot capacity (P(deg>48) ~ 1e-15 per node)
#define LOG2E 1.44269504f

typedef _Float16 h2 __attribute__((ext_vector_type(2)));
typedef _Float16 h8 __attribute__((ext_vector_type(8)));

__device__ __forceinline__ float shflx(float v, int mask) {
    return __shfl_xor(v, mask, 64);
}

// Butterfly sums on the VALU pipe via DPP.
// 0xB1 = quad_perm(1,0,3,2) == xor1; 0x4E = quad_perm(2,3,0,1) == xor2.
// 0x128 = row_ror:8: within a 16-lane row, (i+8)%16 == i^8 exactly -> xor8.
// 0x124 = row_ror:4: (i+4)%16 == i^4 or i^4^8; equals xor4 PROVIDED the value
// is already xor8-invariant (so apply AFTER the xor8 step).
template <int CTRL>
__device__ __forceinline__ float dpp_sum(float x) {
    int yi = __builtin_amdgcn_mov_dpp(__builtin_bit_cast(int, x), CTRL, 0xF, 0xF, true);
    return x + __builtin_bit_cast(float, yi);
}

// xor16 / xor32 butterfly sums: PROVEN __shfl_xor path.
// NOTE (round 14/15 post-mortem): permlane16/32_swap with the same value for
// both operands aliases to an in-place row swap (r[0]==r[1]) -> 2*swapped(x).
// Do not reintroduce without distinct operands.
__device__ __forceinline__ float xor16_sum(float x) { return x + shflx(x, 16); }
__device__ __forceinline__ float xor32_sum(float x) { return x + shflx(x, 32); }

// async global->LDS, 16B per lane; LDS dest = wave-uniform base + lane*16.
__device__ __forceinline__ void gload_lds16(const void* g, void* l) {
    __builtin_amdgcn_global_load_lds(
        (const __attribute__((address_space(1))) void*)g,
        (__attribute__((address_space(3))) void*)l, 16, 0, 0);
}

// Fused prep: blocks [0, nb_norm) L2-normalize each 16-wide capsule of x and
// pack to f16 (wave per node, lane l owns cols 2l,2l+1). Blocks >= nb_norm
// fill the per-target slot table with one atomic pass. Block 0's first 64
// threads also zero the dummy row n (read by routing for empty slots).
__global__ void prep_kernel(const float* __restrict__ x, h2* __restrict__ xh,
                            const int* __restrict__ src, const int* __restrict__ trg,
                            int* __restrict__ cnt, int* __restrict__ slots,
                            int n, int m, int nb_norm) {
    if ((int)blockIdx.x < nb_norm) {
        if (blockIdx.x == 0 && threadIdx.x < 64) {
            h2 zz = {};
            xh[(size_t)n * 64 + threadIdx.x] = zz;   // dummy row
        }
        int node = (int)((blockIdx.x * blockDim.x + threadIdx.x) >> 6);
        int lane = threadIdx.x & 63;
        if (node >= n) return;
        float2 v = *reinterpret_cast<const float2*>(x + (size_t)node * DCOLS + 2 * lane);
        float sq = v.x * v.x + v.y * v.y;
        sq += shflx(sq, 1); sq += shflx(sq, 2); sq += shflx(sq, 4);  // capsule = 8 lanes
        float inv = 1.0f / fmaxf(sqrtf(sq), EPS_N);
        h2 o;
        o[0] = (_Float16)(v.x * inv);
        o[1] = (_Float16)(v.y * inv);
        xh[(size_t)node * 64 + lane] = o;
    } else {
        int e = (blockIdx.x - nb_norm) * blockDim.x + threadIdx.x;
        if (e < m) {
            int t = trg[e];
            int p = atomicAdd(&cnt[t], 1);
            if (p < CAP) slots[t * CAP + p] = src[e];
        }
    }
}

// One edge slot. z = lane's 8 flat cols (f16) of the normalized source row
// (all-zero for empty slots -> p=0, ex=1, zs=8: w*0 contribution, no NaN).
// Snh[t] = packed S (pre-scaled by log2e) for cols 2t,2t+1. p-reduce over the
// capsule's 2 lanes (xor1), softmax-sum over 8 capsules (xor2, xor8, xor4 —
// all DPP on the VALU pipe; ordering: xor4 after xor8, see dpp_sum note).
// No max-subtraction: unit capsules, |S[j]| <= 8 -> |p*log2e| <= 47, f32-safe.
__device__ __forceinline__ void process_edge(const h8 z, const h2 Snh[4], float acc[8]) {
    float part = 0.0f;
    part = __builtin_amdgcn_fdot2(__builtin_shufflevector(z, z, 0, 1), Snh[0], part, false);
    part = __builtin_amdgcn_fdot2(__builtin_shufflevector(z, z, 2, 3), Snh[1], part, false);
    part = __builtin_amdgcn_fdot2(__builtin_shufflevector(z, z, 4, 5), Snh[2], part, false);
    part = __builtin_amdgcn_fdot2(__builtin_shufflevector(z, z, 6, 7), Snh[3], part, false);
    float p = dpp_sum<0xB1>(part);             // xor1 (VALU)
    float ex = exp2f(p);                       // S pre-scaled by log2e
    float zs = dpp_sum<0x4E>(ex);              // xor2 (VALU)
    zs = dpp_sum<0x128>(zs);                   // xor8 (VALU, row_ror:8 exact)
    zs = dpp_sum<0x124>(zs);                   // xor4 (VALU, valid after xor8)
    float w = ex * __builtin_amdgcn_rcpf(zs);
#pragma unroll
    for (int q = 0; q < 8; ++q) acc[q] = fmaf(w, (float)z[q], acc[q]);  // v_fma_mix
}

// Wave per node (4 waves/block). lane = 16*slot + l16. Lane owns FLAT cols
// 8*l16..8*l16+7. S[l16] is lane-local; p-term for flat col f uses S[f & 15].
// z rows DMA'd to LDS (global_load_lds). Per-edge softmax entirely on VALU
// (DPP); DS pipe only carries S-broadcast, zcache reads, cross-slot reduce.
__global__ __launch_bounds__(256) void routing_kernel(
    const h2* __restrict__ xh, const int* __restrict__ cnt,
    const int* __restrict__ slots, float* __restrict__ out, int n)
{
    __shared__ h8 zcache[4][CE][16];
    int wave = threadIdx.x >> 6;
    int node = blockIdx.x * 4 + wave;
    int lane = threadIdx.x & 63;
    if (node >= n) return;
    int l16 = lane & 15;
    int slot = lane >> 4;

    const h8* xrows = reinterpret_cast<const h8*>(xh);  // 16 h8 per row

    h8 xvh = xrows[(size_t)node * 16 + l16];
    float cc[8];
#pragma unroll
    for (int q = 0; q < 8; ++q) cc[q] = (float)xvh[q];

    int deg = min(cnt[node], CAP);
    int base = node * CAP;
    int np = min((deg + EPP - 1) / EPP, NCACHE);   // active cached passes

    // One coalesced slot-index load (lane < CE), broadcast per pass via shfl.
    int idxl = n;
    if (lane < CE && lane < deg) idxl = slots[base + lane];

    // Issue all active passes' DMA back-to-back; lane L of pass pp fills
    // zcache[wave][pp*EPP + (L>>4)][L&15] = base + L*16 (lane-linear).
#pragma unroll 1
    for (int pp = 0; pp < np; ++pp) {
        int u = __shfl(idxl, pp * EPP + slot, 64);  // == n when eidx >= deg
        const char* gsrc = (const char*)xh + ((size_t)u * 256 + l16 * 16);
        gload_lds16(gsrc, &zcache[wave][pp * EPP][0]);
    }
    asm volatile("s_waitcnt vmcnt(0)" ::: "memory");

    int src_base = (lane & ~15) | (8 * (l16 & 1));

    for (int t = 0; t < ROUTIT; ++t) {
        // S[l16] lane-local (scaled by log2e); pair-pack (xor1 DPP + pkrtz),
        // then 4 bpermutes fetch the 8 S values this lane needs.
        float Sl = ((cc[0] + cc[1]) + (cc[2] + cc[3])) + ((cc[4] + cc[5]) + (cc[6] + cc[7]));
        Sl *= LOG2E;
        int Spi = __builtin_amdgcn_mov_dpp(__builtin_bit_cast(int, Sl), 0xB1, 0xF, 0xF, true);
        float Sp = __builtin_bit_cast(float, Spi);
        auto Wl = __builtin_amdgcn_cvt_pkrtz(Sl, Sp);  // even lanes: (S[e], S[e+1])
        int Wi = __builtin_bit_cast(int, Wl);
        h2 Snh[4];
#pragma unroll
        for (int tq = 0; tq < 4; ++tq)
            Snh[tq] = __builtin_bit_cast(h2, __shfl(Wi, src_base + 2 * tq, 64));

        float acc[8];
#pragma unroll
        for (int q = 0; q < 8; ++q) acc[q] = 0.0f;

        // unroll-1: exactly one z-row live at a time (VGPR control).
#pragma unroll 1
        for (int pp = 0; pp < np; ++pp) {
            h8 z = zcache[wave][pp * EPP + slot][l16];
            process_edge(z, Snh, acc);
        }
        // streaming tail (P(deg>20) ~ 1.5% of nodes)
#pragma unroll 1
        for (int eb = CE; eb < deg; eb += EPP) {
            int eidx = eb + slot;
            h8 z = {};
            if (eidx < deg) z = xrows[(size_t)slots[base + eidx] * 16 + l16];
            process_edge(z, Snh, acc);
        }

        // reduce across the 4 edge slots (proven shfl path)
#pragma unroll
        for (int q = 0; q < 8; ++q) {
            acc[q] = xor16_sum(acc[q]);
            acc[q] = xor32_sum(acc[q]);
        }
#pragma unroll
        for (int q = 0; q < 8; ++q) cc[q] = acc[q] + (float)xvh[q];

        if (t < ROUTIT - 1) {
            float sq = cc[0] * cc[0];
#pragma unroll
            for (int q = 1; q < 8; ++q) sq = fmaf(cc[q], cc[q], sq);
            sq = dpp_sum<0xB1>(sq);   // capsule = 2 adjacent lanes (xor1)
            float inv = 1.0f / fmaxf(sqrtf(sq), EPS_N);
#pragma unroll
            for (int q = 0; q < 8; ++q) cc[q] *= inv;
        }
    }

    if (slot == 0) {
        float4* orow = reinterpret_cast<float4*>(out + (size_t)node * DCOLS + 8 * l16);
        orow[0] = make_float4(cc[0], cc[1], cc[2], cc[3]);
        orow[1] = make_float4(cc[4], cc[5], cc[6], cc[7]);
    }
}

extern "C" void kernel_launch(void* const* d_in, const int* in_sizes, int n_in,
                              void* d_out, int out_size, void* d_ws, size_t ws_size,
                              hipStream_t stream) {
    const float* x = (const float*)d_in[0];
    const int* ei = (const int*)d_in[1];
    float* out = (float*)d_out;
    int n = in_sizes[0] / DCOLS;
    int m = in_sizes[1] / 2;
    const int* src = ei;
    const int* trg = ei + m;

    char* ws = (char*)d_ws;
    h2* xh = (h2*)ws;             ws += (size_t)(n + 1) * DCOLS * sizeof(_Float16);
    int* cnt = (int*)ws;          ws += (size_t)n * sizeof(int);
    int* slots = (int*)ws;        ws += (size_t)n * CAP * sizeof(int);

    (void)hipMemsetAsync(cnt, 0, (size_t)n * sizeof(int), stream);

    int nb_norm = (n + 3) / 4;
    int nb_fill = (m + 255) / 256;
    prep_kernel<<<nb_norm + nb_fill, 256, 0, stream>>>(x, xh, src, trg, cnt, slots,
                                                       n, m, nb_norm);
    routing_kernel<<<(n + 3) / 4, 256, 0, stream>>>(xh, cnt, slots, out, n);
}